// Round 9
// baseline (1011.748 us; speedup 1.0000x reference)
//
#include <hip/hip_runtime.h>
#include <hip/hip_bf16.h>
#include <math.h>
#include <type_traits>

#define SEQ  512
#define BSZ  128
#define EMBD 128
#define H4   512
#define HD   128
#define NTAG 7
#define BOSX 4
#define EOSX 5
#define NEGC (-10000.0f)
#define TILE 16

typedef float v2f __attribute__((ext_vector_type(2)));

template<typename T> __device__ __forceinline__ void st4(T* p, float4 v);
template<> __device__ __forceinline__ void st4<float>(float* p, float4 v) { *(float4*)p = v; }
template<> __device__ __forceinline__ void st4<__hip_bfloat16>(__hip_bfloat16* p, float4 v) {
    p[0] = __float2bfloat16(v.x); p[1] = __float2bfloat16(v.y);
    p[2] = __float2bfloat16(v.z); p[3] = __float2bfloat16(v.w);
}

__device__ __forceinline__ float frcp(float x) { return __builtin_amdgcn_rcpf(x); }
__device__ __forceinline__ unsigned short f2bf(float x) {
    const __hip_bfloat16 h = __float2bfloat16(x);
    return __builtin_bit_cast(unsigned short, h);
}
__device__ __forceinline__ float bflo(unsigned d) { return __builtin_bit_cast(float, d << 16); }
__device__ __forceinline__ float bfhi(unsigned d) { return __builtin_bit_cast(float, d & 0xFFFF0000u); }

template<int C> __device__ __forceinline__ float dppaddf(float x) {
    const int y = __builtin_amdgcn_update_dpp(0, __builtin_bit_cast(int, x), C, 0xF, 0xF, true);
    return x + __builtin_bit_cast(float, y);
}
template<int C> __device__ __forceinline__ float dppmovf(float x) {
    return __builtin_bit_cast(float,
        __builtin_amdgcn_update_dpp(0, __builtin_bit_cast(int, x), C, 0xF, 0xF, true));
}
// full k-reduce (broadcast to all k-lanes); k = lane bits {0,1,3}
__device__ __forceinline__ float kreduce(float x) {
    x = dppaddf<0xB1>(x);   // xor bit0
    x = dppaddf<0x4E>(x);   // xor bit1
    x = dppaddf<0x128>(x);  // xor bit3 (row_ror:8)
    return x;
}

// bf16 chunk layout: chunk k (16 bf16 = 8 dwords) at dword offset 12*k.
// 12k mod 32 = {0,12,24,4,16,28,8,20}: both b128s of the wave's 8 distinct
// chunk addresses cover all 32 banks exactly once -> zero conflicts.
#define CH_DW  12
#define ROW_DW 96

// unpack 8 dwords (16 bf16) -> r[4] float4 (element order preserved)
__device__ __forceinline__ void unpack16(const uint4 p0, const uint4 p1, float4* r) {
    r[0].x = bflo(p0.x); r[0].y = bfhi(p0.x); r[0].z = bflo(p0.y); r[0].w = bfhi(p0.y);
    r[1].x = bflo(p0.z); r[1].y = bfhi(p0.z); r[1].z = bflo(p0.w); r[1].w = bfhi(p0.w);
    r[2].x = bflo(p1.x); r[2].y = bfhi(p1.x); r[2].z = bflo(p1.y); r[2].w = bfhi(p1.y);
    r[3].x = bflo(p1.z); r[3].y = bfhi(p1.z); r[3].z = bflo(p1.w); r[3].w = bfhi(p1.w);
}

__device__ __forceinline__ float dot16(const v2f* __restrict__ w2, const float4* __restrict__ r) {
    v2f a = {0.f, 0.f};
    #pragma unroll
    for (int j = 0; j < 4; ++j) {
        v2f lo; lo.x = r[j].x; lo.y = r[j].y;
        v2f hi; hi.x = r[j].z; hi.y = r[j].w;
        a = __builtin_elementwise_fma(w2[2 * j], lo, a);
        a = __builtin_elementwise_fma(w2[2 * j + 1], hi, a);
    }
    return a.x + a.y;
}
__device__ __forceinline__ void ldw2(v2f* w2, const float4* wr) {
    #pragma unroll
    for (int j = 0; j < 4; ++j) {
        const float4 f4 = wr[j];
        w2[2 * j].x = f4.x;     w2[2 * j].y = f4.y;
        w2[2 * j + 1].x = f4.z; w2[2 * j + 1].y = f4.w;
    }
}

// =============== K1: fused projection + recurrence + emissions ===============
// grid 2*BSZ (1 block/CU), block 1024 = 128 u x 8 k (k = lane bits {0,1,3}).
// x and h staged in LDS as bf16 (R8: LDS pipe ~900 cyc/step was a co-bottleneck;
// bf16 halves chunk reads 4 b128 -> 2, unpack shared across the 4 gate dots).
// All arithmetic fp32; c fp32 in registers.
template<typename XWT>
__global__ __launch_bounds__(1024, 1)
void bilstm_kernel(const int* __restrict__ sen, const float* __restrict__ emb,
                   const float* __restrict__ Wih_f, const float* __restrict__ b_f,
                   const float* __restrict__ Wih_b, const float* __restrict__ b_b,
                   const float* __restrict__ Whh_f, const float* __restrict__ Whh_b,
                   const float* __restrict__ W_out,
                   XWT* __restrict__ xw, float* __restrict__ eft, float* __restrict__ ebt)
{
    const int tid = threadIdx.x;
    const int wid = tid >> 6;
    const int lane = tid & 63;
    const int k = (lane & 3) | ((lane >> 1) & 4);          // lane bits 0,1,3
    const int m = ((lane >> 2) & 1) | ((lane >> 3) & 6);   // lane bits 2,4,5
    const int u = wid * 8 + m;
    const bool bk0 = (lane & 1) != 0;
    const bool bk1 = (lane & 2) != 0;
    const int q2 = (bk1 ? 2 : 0) + (bk0 ? 1 : 0);          // owned gate id (i,f,g,o)
    const int chain = blockIdx.x;
    const int dir = chain & 1;
    const int b = chain >> 1;

    __shared__ __align__(16) unsigned smem_u[TILE * H4];   // 32 KB: x-stage (A) / xw tile (B)
    __shared__ __align__(16) unsigned hdb_u[2 * ROW_DW];   // h double-buffer, bf16 chunks

    XWT* __restrict__ xw_c = xw + (size_t)chain * (SEQ * H4);
    v2f w2[4][8];                                          // 64 VGPRs of weights

    // ---------------- Phase A: input projection ----------------
    {
        const float* __restrict__ Wih  = dir ? Wih_b : Wih_f;
        const float* __restrict__ bias = dir ? b_b : b_f;
        #pragma unroll
        for (int g = 0; g < 4; ++g)
            ldw2(w2[g], (const float4*)(Wih + (g * HD + u) * EMBD + k * 16));
        float4 bj;
        bj.x = bias[u]; bj.y = bias[HD + u]; bj.z = bias[2 * HD + u]; bj.w = bias[3 * HD + u];

        for (int tt = 0; tt < SEQ; tt += 32) {
            {   // stage 32 embedding rows as bf16 chunks (b64 writes, even-dword aligned)
                const int srow = tid >> 5;
                const int c = tid & 31;                    // float4 group 0..31
                const int tok = sen[(tt + srow) * BSZ + b];
                const float4 v = ((const float4*)(emb + (size_t)tok * EMBD))[c];
                const unsigned d0 = (unsigned)f2bf(v.x) | ((unsigned)f2bf(v.y) << 16);
                const unsigned d1 = (unsigned)f2bf(v.z) | ((unsigned)f2bf(v.w) << 16);
                uint2 dd; dd.x = d0; dd.y = d1;
                *(uint2*)&smem_u[srow * ROW_DW + (c >> 2) * CH_DW + (c & 3) * 2] = dd;
            }
            __syncthreads();
            for (int i = 0; i < 32; ++i) {
                const uint4* xr = (const uint4*)(smem_u + i * ROW_DW + k * CH_DW);
                const uint4 p0 = xr[0], p1 = xr[1];
                float4 r[4];
                unpack16(p0, p1, r);
                const float z0 = kreduce(dot16(w2[0], r));
                const float z1 = kreduce(dot16(w2[1], r));
                const float z2 = kreduce(dot16(w2[2], r));
                const float z3 = kreduce(dot16(w2[3], r));
                if (k == 0) {
                    float4 o; o.x = z0 + bj.x; o.y = z1 + bj.y; o.z = z2 + bj.z; o.w = z3 + bj.w;
                    st4(&xw_c[(tt + i) * H4 + u * 4], o);
                }
            }
            __syncthreads();
        }
    }

    // ---------------- Phase B: recurrence + emissions ----------------
    {
        const float* __restrict__ Whh = dir ? Whh_b : Whh_f;
        #pragma unroll
        for (int g = 0; g < 4; ++g)
            ldw2(w2[g], (const float4*)(Whh + (g * HD + u) * HD + k * 16));
        v2f wo[8];                                         // wave-0 emission weights
        {
            const int mm = (m < NTAG) ? m : 0;
            ldw2(wo, (const float4*)(W_out + mm * 256 + dir * HD + k * 16));
        }
        if (tid < 2 * ROW_DW) hdb_u[tid] = 0u;             // h=0 (bf16 zero)
        float c = 0.0f, v0 = 0.0f, v1 = 0.0f;
        float* __restrict__ eX = (dir ? ebt : eft) + (size_t)b * (SEQ * 8);
        float (*xwt)[H4] = (float (*)[H4])smem_u;
        __syncthreads();

        const int t0 = dir ? (SEQ - 1) : 0;
        const int ts = dir ? -1 : 1;
        for (int s = 0; s <= SEQ; ++s) {
            if ((s & (TILE - 1)) == 0) {
                if (s < SEQ) {                             // stage xw for steps s..s+15
                    const int tg = t0 + ts * (s + wid);    // wave wid stages slot wid
                    float4* dst = (float4*)xwt[wid];
                    if constexpr (std::is_same_v<XWT, float>) {
                        const float4* src = (const float4*)(xw_c + tg * H4);
                        dst[lane] = src[lane];
                        dst[lane + 64] = src[lane + 64];
                    } else {
                        const uint4 raw = ((const uint4*)(xw_c + tg * H4))[lane];
                        const unsigned rr[4] = {raw.x, raw.y, raw.z, raw.w};
                        float4 lo4, hi4;
                        float* lp = (float*)&lo4; float* hp = (float*)&hi4;
                        #pragma unroll
                        for (int j = 0; j < 2; ++j) {
                            lp[2*j]   = bflo(rr[j]);
                            lp[2*j+1] = bfhi(rr[j]);
                            hp[2*j]   = bflo(rr[j+2]);
                            hp[2*j+1] = bfhi(rr[j+2]);
                        }
                        dst[2 * lane] = lo4;
                        dst[2 * lane + 1] = hi4;
                    }
                }
                __syncthreads();
            }
            const int cur = s & 1;
            float4 r[4];                                   // chunk k of h_{t-ts} (bf16->fp32)
            {
                const uint4* hr = (const uint4*)(hdb_u + cur * ROW_DW + k * CH_DW);
                const uint4 p0 = hr[0], p1 = hr[1];
                unpack16(p0, p1, r);
            }
            if (s < SEQ) {
                const float xq = xwt[s & (TILE - 1)][u * 4 + q2];   // my gate's xw (b32)
                const float pi = dot16(w2[0], r);
                const float pf = dot16(w2[1], r);
                const float pg = dot16(w2[2], r);
                const float po = dot16(w2[3], r);
                // reduce-scatter: lane ends owning gate q2
                const float A = (bk0 ? pf : pi) + dppmovf<0xB1>(bk0 ? pi : pf);
                const float B = (bk0 ? po : pg) + dppmovf<0xB1>(bk0 ? pg : po);
                float z = (bk1 ? B : A) + dppmovf<0x4E>(bk1 ? A : B);
                z += dppmovf<0x128>(z);
                z += xq;
                // one activation per lane (gate 2 = tanh via 2*sigma(2z)-1)
                const bool isg = bk1 && !bk0;
                const float x2 = isg ? (z + z) : z;
                float y = frcp(1.0f + __expf(-x2));
                y = isg ? (2.0f * y - 1.0f) : y;
                // all-gather the 4 activated gates
                const float r1 = dppmovf<0xB1>(y);
                const float r2 = dppmovf<0x4E>(y);
                const float r3 = dppmovf<0x4E>(r1);
                const float i0 = bk0 ? r1 : y,  i1 = bk0 ? y : r1;
                const float i2 = bk0 ? r3 : r2, i3 = bk0 ? r2 : r3;
                const float gi = bk1 ? i2 : i0;
                const float gf = bk1 ? i3 : i1;
                const float gg = bk1 ? i0 : i2;
                const float go = bk1 ? i1 : i3;
                c = gf * c + gi * gg;                      // redundant across k-lanes
                const float th = 2.0f * frcp(1.0f + __expf(-2.0f * c)) - 1.0f;
                const float h = go * th;
                if (k == 0) {                              // write h as bf16 halfword
                    ((unsigned short*)hdb_u)[((cur ^ 1) * ROW_DW + (u >> 4) * CH_DW) * 2 + (u & 15)]
                        = f2bf(h);
                }
            }
            if (wid == 0 && s >= 1) {                      // emission for time e = s-1
                const float ev = kreduce(dot16(wo, r));
                const int e = s - 1;
                if ((e & 7) == k) { if (e & 8) v1 = ev; else v0 = ev; }
                if ((s & (TILE - 1)) == 0 && m < NTAG) {   // flush e in [s-16, s-1]
                    const int eA = s - TILE + k;
                    eX[(t0 + ts * eA) * 8 + m] = v0;
                    eX[(t0 + ts * (eA + 8)) * 8 + m] = v1;
                }
            }
            __syncthreads();
        }
    }
}

// ======================= K2: Viterbi scan + backtrace =======================
// grid BSZ, block 256. Wave 0 runs the scan (lane = next*8+prev); backtrace
// walks ALL 7 terminal tags concurrently (one lockstep dependent-LDS chain
// instead of 512 serial hops); output writes parallel over 256 threads.
__global__ __launch_bounds__(256, 1)
void vit_kernel(const float* __restrict__ eft, const float* __restrict__ ebt,
                const float* __restrict__ b_out, const float* __restrict__ trans,
                float* __restrict__ out)
{
    const int b = blockIdx.x;
    const int tid = threadIdx.x;
    __shared__ __align__(16) float ftl[SEQ * 8];
    __shared__ int bptr_lds[SEQ * 8];
    __shared__ unsigned char path[SEQ * 8];
    __shared__ int sbest;

    {   // stage ef+eb with all 256 threads
        const float4* sf = (const float4*)(eft + (size_t)b * (SEQ * 8));
        const float4* sb = (const float4*)(ebt + (size_t)b * (SEQ * 8));
        float4* dst = (float4*)ftl;
        #pragma unroll
        for (int i = 0; i < SEQ * 2 / 256; ++i) {
            const int idx = tid + i * 256;
            float4 a = sf[idx];
            const float4 c4 = sb[idx];
            a.x += c4.x; a.y += c4.y; a.z += c4.z; a.w += c4.w;
            dst[idx] = a;
        }
    }
    __syncthreads();

    if (tid < 64) {
        const int lane = tid;
        const int next = lane >> 3;
        const int prev = lane & 7;
        const bool pv = (prev < NTAG);
        const bool nv = (next < NTAG);
        const float trv = (pv && nv) ? (trans[next * NTAG + prev] + b_out[next]) : -3.0e38f;
        float fvp = pv ? ((prev == BOSX) ? 0.0f : NEGC) : -3.0e38f;
        for (int t = 0; t < SEQ; ++t) {
            float mv = fvp + trv;
            int am = prev;
            #pragma unroll
            for (int off = 1; off < 8; off <<= 1) {        // first-max-index semantics
                const float om = __shfl_xor(mv, off);
                const int oa = __shfl_xor(am, off);
                if (om > mv || (om == mv && oa < am)) { mv = om; am = oa; }
            }
            const float fvnew = mv + ftl[t * 8 + next];
            if (prev == 0) bptr_lds[t * 8 + next] = am;
            fvp = __shfl(fvnew, prev << 3);
            if (!pv) fvp = -3.0e38f;
        }
        float term = pv ? (fvp + trans[EOSX * NTAG + prev]) : -3.0e38f;
        int am = prev;
        #pragma unroll
        for (int off = 1; off < 8; off <<= 1) {
            const float om = __shfl_xor(term, off);
            const int oa = __shfl_xor(am, off);
            if (om > term || (om == term && oa < am)) { term = om; am = oa; }
        }
        if (lane == 0) { out[b] = term; sbest = am; }
    }
    __syncthreads();

    if (tid < NTAG) {                                      // 7 concurrent walks, lockstep
        int cur = tid;
        for (int t = SEQ - 1; t >= 0; --t) {
            path[t * 8 + tid] = (unsigned char)cur;
            cur = bptr_lds[t * 8 + cur];
        }
    }
    __syncthreads();
    const int am = sbest;
    for (int t = tid; t < SEQ; t += 256)
        out[BSZ + t * BSZ + b] = (float)path[t * 8 + am];
}

// ======================= launch =======================
extern "C" void kernel_launch(void* const* d_in, const int* in_sizes, int n_in,
                              void* d_out, int out_size, void* d_ws, size_t ws_size,
                              hipStream_t stream)
{
    const int*   sen   = (const int*)d_in[0];
    const float* emb   = (const float*)d_in[1];
    const float* Wih_f = (const float*)d_in[2];
    const float* Whh_f = (const float*)d_in[3];
    const float* b_f   = (const float*)d_in[4];
    const float* Wih_b = (const float*)d_in[5];
    const float* Whh_b = (const float*)d_in[6];
    const float* b_b   = (const float*)d_in[7];
    const float* W_out = (const float*)d_in[8];
    const float* b_out = (const float*)d_in[9];
    const float* trans = (const float*)d_in[10];
    float* out = (float*)d_out;

    char* ws = (char*)d_ws;
    const size_t xw_elems = (size_t)2 * BSZ * SEQ * H4;   // 67,108,864
    const size_t ft_bytes = (size_t)BSZ * SEQ * 8 * 4;    // 2 MB each

    if (ws_size >= xw_elems * 4 + 2 * ft_bytes) {
        float* xw = (float*)ws;
        float* eft = (float*)(ws + xw_elems * 4);
        float* ebt = (float*)(ws + xw_elems * 4 + ft_bytes);
        bilstm_kernel<float><<<dim3(2 * BSZ), dim3(1024), 0, stream>>>(
            sen, emb, Wih_f, b_f, Wih_b, b_b, Whh_f, Whh_b, W_out, xw, eft, ebt);
        vit_kernel<<<dim3(BSZ), dim3(256), 0, stream>>>(eft, ebt, b_out, trans, out);
    } else {
        __hip_bfloat16* xw = (__hip_bfloat16*)ws;
        float* eft = (float*)(ws + xw_elems * 2);
        float* ebt = (float*)(ws + xw_elems * 2 + ft_bytes);
        bilstm_kernel<__hip_bfloat16><<<dim3(2 * BSZ), dim3(1024), 0, stream>>>(
            sen, emb, Wih_f, b_f, Wih_b, b_b, Whh_f, Whh_b, W_out, xw, eft, ebt);
        vit_kernel<<<dim3(BSZ), dim3(256), 0, stream>>>(eft, ebt, b_out, trans, out);
    }
}

// Round 10
// 897.288 us; speedup vs baseline: 1.1276x; 1.1276x over previous
//
#include <hip/hip_runtime.h>
#include <hip/hip_bf16.h>
#include <math.h>
#include <type_traits>

#define SEQ  512
#define BSZ  128
#define EMBD 128
#define H4   512
#define HD   128
#define NTAG 7
#define BOSX 4
#define EOSX 5
#define NEGC (-10000.0f)
#define TILE 16

typedef _Float16 h2 __attribute__((ext_vector_type(2)));

template<typename T> __device__ __forceinline__ void st4(T* p, float4 v);
template<> __device__ __forceinline__ void st4<float>(float* p, float4 v) { *(float4*)p = v; }
template<> __device__ __forceinline__ void st4<__hip_bfloat16>(__hip_bfloat16* p, float4 v) {
    p[0] = __float2bfloat16(v.x); p[1] = __float2bfloat16(v.y);
    p[2] = __float2bfloat16(v.z); p[3] = __float2bfloat16(v.w);
}

__device__ __forceinline__ float frcp(float x) { return __builtin_amdgcn_rcpf(x); }
__device__ __forceinline__ float bflo(unsigned d) { return __builtin_bit_cast(float, d << 16); }
__device__ __forceinline__ float bfhi(unsigned d) { return __builtin_bit_cast(float, d & 0xFFFF0000u); }

// f16 dot2: 2 MACs/inst, fp32 accumulate (v_dot2_f32_f16)
__device__ __forceinline__ float fdot2(h2 a, h2 b, float c) {
#if __has_builtin(__builtin_amdgcn_fdot2)
    return __builtin_amdgcn_fdot2(a, b, c, false);
#else
    return c + (float)a.x * (float)b.x + (float)a.y * (float)b.y;
#endif
}

template<int C> __device__ __forceinline__ float dppaddf(float x) {
    const int y = __builtin_amdgcn_update_dpp(0, __builtin_bit_cast(int, x), C, 0xF, 0xF, true);
    return x + __builtin_bit_cast(float, y);
}
template<int C> __device__ __forceinline__ float dppmovf(float x) {
    return __builtin_bit_cast(float,
        __builtin_amdgcn_update_dpp(0, __builtin_bit_cast(int, x), C, 0xF, 0xF, true));
}
// full k-reduce (broadcast to all k-lanes); k = lane bits {0,1,3}
__device__ __forceinline__ float kreduce(float x) {
    x = dppaddf<0xB1>(x);   // xor bit0
    x = dppaddf<0x4E>(x);   // xor bit1
    x = dppaddf<0x128>(x);  // xor bit3 (row_ror:8)
    return x;
}

// f16 chunk layout: chunk k (16 f16 = 8 dwords) at dword offset 12*k.
// 12k mod 32 = {0,12,24,4,16,28,8,20}: both b128s of the wave's 8 distinct
// chunk addresses cover all 32 banks exactly once -> zero conflicts.
#define CH_DW  12
#define ROW_DW 96

// 16-element f16 chunk dot: w[8] half2 x x[8] half2 -> fp32
__device__ __forceinline__ float dot16h(const h2* __restrict__ w, const h2* __restrict__ x) {
    float a = 0.f;
    #pragma unroll
    for (int j = 0; j < 8; ++j) a = fdot2(w[j], x[j], a);
    return a;
}
// load 16 fp32 weights -> 8 half2 (RNE converts, one-time)
__device__ __forceinline__ void ldwh(h2* w, const float4* wr) {
    #pragma unroll
    for (int j = 0; j < 4; ++j) {
        const float4 f4 = wr[j];
        h2 a; a.x = (_Float16)f4.x; a.y = (_Float16)f4.y;
        h2 b; b.x = (_Float16)f4.z; b.y = (_Float16)f4.w;
        w[2 * j] = a; w[2 * j + 1] = b;
    }
}
__device__ __forceinline__ void unp8(const uint4 p0, const uint4 p1, h2* x) {
    x[0] = __builtin_bit_cast(h2, p0.x); x[1] = __builtin_bit_cast(h2, p0.y);
    x[2] = __builtin_bit_cast(h2, p0.z); x[3] = __builtin_bit_cast(h2, p0.w);
    x[4] = __builtin_bit_cast(h2, p1.x); x[5] = __builtin_bit_cast(h2, p1.y);
    x[6] = __builtin_bit_cast(h2, p1.z); x[7] = __builtin_bit_cast(h2, p1.w);
}

// =============== K1: fused projection + recurrence + emissions ===============
// grid 2*BSZ (1 block/CU), block 1024 = 128 u x 8 k (k = lane bits {0,1,3}).
// R4-R9 invariant ~3500 cyc/step traced to VGPR_Count=44-64 < the 64-reg
// weight array: allocator (targeting 8 waves/SIMD) never kept weights
// register-resident -> Whh re-streamed from L2 every step (256 KB/CU/step ~=
// per-XCD L2 BW floor). Fix: waves_per_eu(4,4) gives the 128-VGPR budget, and
// f16 weights (v_dot2_f32_f16, fp32 acc) halve the array to 32 VGPRs.
// h/x in LDS as f16 chunks: 2 ds_read_b128, consumed directly (no unpack).
template<typename XWT>
__global__ __launch_bounds__(1024) __attribute__((amdgpu_waves_per_eu(4, 4)))
void bilstm_kernel(const int* __restrict__ sen, const float* __restrict__ emb,
                   const float* __restrict__ Wih_f, const float* __restrict__ b_f,
                   const float* __restrict__ Wih_b, const float* __restrict__ b_b,
                   const float* __restrict__ Whh_f, const float* __restrict__ Whh_b,
                   const float* __restrict__ W_out,
                   XWT* __restrict__ xw, float* __restrict__ eft, float* __restrict__ ebt)
{
    const int tid = threadIdx.x;
    const int wid = tid >> 6;
    const int lane = tid & 63;
    const int k = (lane & 3) | ((lane >> 1) & 4);          // lane bits 0,1,3
    const int m = ((lane >> 2) & 1) | ((lane >> 3) & 6);   // lane bits 2,4,5
    const int u = wid * 8 + m;
    const bool bk0 = (lane & 1) != 0;
    const bool bk1 = (lane & 2) != 0;
    const int q2 = (bk1 ? 2 : 0) + (bk0 ? 1 : 0);          // owned gate id
    const int chain = blockIdx.x;
    const int dir = chain & 1;
    const int b = chain >> 1;

    __shared__ __align__(16) unsigned smem_u[TILE * H4];   // 32 KB: x-stage (A) / xw tile (B)
    __shared__ __align__(16) unsigned hdb_u[2 * ROW_DW];   // h double-buffer, f16 chunks

    XWT* __restrict__ xw_c = xw + (size_t)chain * (SEQ * H4);
    h2 w2[4][8];                                           // 32 VGPRs of f16 weights

    // ---------------- Phase A: input projection ----------------
    {
        const float* __restrict__ Wih  = dir ? Wih_b : Wih_f;
        const float* __restrict__ bias = dir ? b_b : b_f;
        #pragma unroll
        for (int g = 0; g < 4; ++g)
            ldwh(w2[g], (const float4*)(Wih + (g * HD + u) * EMBD + k * 16));
        float4 bj;
        bj.x = bias[u]; bj.y = bias[HD + u]; bj.z = bias[2 * HD + u]; bj.w = bias[3 * HD + u];

        for (int tt = 0; tt < SEQ; tt += 32) {
            {   // stage 32 embedding rows as f16 chunks (uint2 writes)
                const int srow = tid >> 5;
                const int c = tid & 31;                    // float4 group 0..31
                const int tok = sen[(tt + srow) * BSZ + b];
                const float4 v = ((const float4*)(emb + (size_t)tok * EMBD))[c];
                h2 a; a.x = (_Float16)v.x; a.y = (_Float16)v.y;
                h2 d; d.x = (_Float16)v.z; d.y = (_Float16)v.w;
                uint2 dd; dd.x = __builtin_bit_cast(unsigned, a); dd.y = __builtin_bit_cast(unsigned, d);
                *(uint2*)&smem_u[srow * ROW_DW + (c >> 2) * CH_DW + (c & 3) * 2] = dd;
            }
            __syncthreads();
            for (int i = 0; i < 32; ++i) {
                const uint4* xr = (const uint4*)(smem_u + i * ROW_DW + k * CH_DW);
                const uint4 p0 = xr[0], p1 = xr[1];
                h2 hx[8];
                unp8(p0, p1, hx);
                const float z0 = kreduce(dot16h(w2[0], hx));
                const float z1 = kreduce(dot16h(w2[1], hx));
                const float z2 = kreduce(dot16h(w2[2], hx));
                const float z3 = kreduce(dot16h(w2[3], hx));
                if (k == 0) {
                    float4 o; o.x = z0 + bj.x; o.y = z1 + bj.y; o.z = z2 + bj.z; o.w = z3 + bj.w;
                    st4(&xw_c[(tt + i) * H4 + u * 4], o);
                }
            }
            __syncthreads();
        }
    }

    // ---------------- Phase B: recurrence + emissions ----------------
    {
        const float* __restrict__ Whh = dir ? Whh_b : Whh_f;
        #pragma unroll
        for (int g = 0; g < 4; ++g)
            ldwh(w2[g], (const float4*)(Whh + (g * HD + u) * HD + k * 16));
        h2 wo[8];                                          // wave-0 emission weights (f16)
        {
            const int mm = (m < NTAG) ? m : 0;
            ldwh(wo, (const float4*)(W_out + mm * 256 + dir * HD + k * 16));
        }
        if (tid < 2 * ROW_DW) hdb_u[tid] = 0u;             // h=0
        float c = 0.0f, v0 = 0.0f, v1 = 0.0f;
        float* __restrict__ eX = (dir ? ebt : eft) + (size_t)b * (SEQ * 8);
        float (*xwt)[H4] = (float (*)[H4])smem_u;
        __syncthreads();

        const int t0 = dir ? (SEQ - 1) : 0;
        const int ts = dir ? -1 : 1;
        for (int s = 0; s <= SEQ; ++s) {
            if ((s & (TILE - 1)) == 0) {
                if (s < SEQ) {                             // stage xw for steps s..s+15
                    const int tg = t0 + ts * (s + wid);    // wave wid stages slot wid
                    float4* dst = (float4*)xwt[wid];
                    if constexpr (std::is_same_v<XWT, float>) {
                        const float4* src = (const float4*)(xw_c + tg * H4);
                        dst[lane] = src[lane];
                        dst[lane + 64] = src[lane + 64];
                    } else {
                        const uint4 raw = ((const uint4*)(xw_c + tg * H4))[lane];
                        const unsigned rr[4] = {raw.x, raw.y, raw.z, raw.w};
                        float4 lo4, hi4;
                        float* lp = (float*)&lo4; float* hp = (float*)&hi4;
                        #pragma unroll
                        for (int j = 0; j < 2; ++j) {
                            lp[2*j]   = bflo(rr[j]);
                            lp[2*j+1] = bfhi(rr[j]);
                            hp[2*j]   = bflo(rr[j+2]);
                            hp[2*j+1] = bfhi(rr[j+2]);
                        }
                        dst[2 * lane] = lo4;
                        dst[2 * lane + 1] = hi4;
                    }
                }
                __syncthreads();
            }
            const int cur = s & 1;
            h2 hx[8];                                      // chunk k of h_{t-ts} (f16)
            {
                const uint4* hr = (const uint4*)(hdb_u + cur * ROW_DW + k * CH_DW);
                const uint4 p0 = hr[0], p1 = hr[1];
                unp8(p0, p1, hx);
            }
            if (s < SEQ) {
                const float xq = xwt[s & (TILE - 1)][u * 4 + q2];   // my gate's xw (b32)
                const float pi = dot16h(w2[0], hx);
                const float pf = dot16h(w2[1], hx);
                const float pg = dot16h(w2[2], hx);
                const float po = dot16h(w2[3], hx);
                // reduce-scatter: lane ends owning gate q2
                const float A = (bk0 ? pf : pi) + dppmovf<0xB1>(bk0 ? pi : pf);
                const float B = (bk0 ? po : pg) + dppmovf<0xB1>(bk0 ? pg : po);
                float z = (bk1 ? B : A) + dppmovf<0x4E>(bk1 ? A : B);
                z += dppmovf<0x128>(z);
                z += xq;
                // one activation per lane (gate 2 = tanh via 2*sigma(2z)-1)
                const bool isg = bk1 && !bk0;
                const float x2 = isg ? (z + z) : z;
                float y = frcp(1.0f + __expf(-x2));
                y = isg ? (2.0f * y - 1.0f) : y;
                // all-gather the 4 activated gates
                const float r1 = dppmovf<0xB1>(y);
                const float r2 = dppmovf<0x4E>(y);
                const float r3 = dppmovf<0x4E>(r1);
                const float i0 = bk0 ? r1 : y,  i1 = bk0 ? y : r1;
                const float i2 = bk0 ? r3 : r2, i3 = bk0 ? r2 : r3;
                const float gi = bk1 ? i2 : i0;
                const float gf = bk1 ? i3 : i1;
                const float gg = bk1 ? i0 : i2;
                const float go = bk1 ? i1 : i3;
                c = gf * c + gi * gg;                      // redundant across k-lanes
                const float th = 2.0f * frcp(1.0f + __expf(-2.0f * c)) - 1.0f;
                const float h = go * th;
                if (k == 0) {                              // write h as f16 halfword
                    ((unsigned short*)hdb_u)[((cur ^ 1) * ROW_DW + (u >> 4) * CH_DW) * 2 + (u & 15)]
                        = __builtin_bit_cast(unsigned short, (_Float16)h);
                }
            }
            if (wid == 0 && s >= 1) {                      // emission for time e = s-1
                const float ev = kreduce(dot16h(wo, hx));
                const int e = s - 1;
                if ((e & 7) == k) { if (e & 8) v1 = ev; else v0 = ev; }
                if ((s & (TILE - 1)) == 0 && m < NTAG) {   // flush e in [s-16, s-1]
                    const int eA = s - TILE + k;
                    eX[(t0 + ts * eA) * 8 + m] = v0;
                    eX[(t0 + ts * (eA + 8)) * 8 + m] = v1;
                }
            }
            __syncthreads();
        }
    }
}

// ======================= K2: Viterbi scan + backtrace =======================
// grid BSZ, block 256. Wave 0 runs the scan (lane = next*8+prev); backtrace
// walks all 7 terminal tags concurrently; output writes parallel.
__global__ __launch_bounds__(256, 1)
void vit_kernel(const float* __restrict__ eft, const float* __restrict__ ebt,
                const float* __restrict__ b_out, const float* __restrict__ trans,
                float* __restrict__ out)
{
    const int b = blockIdx.x;
    const int tid = threadIdx.x;
    __shared__ __align__(16) float ftl[SEQ * 8];
    __shared__ int bptr_lds[SEQ * 8];
    __shared__ unsigned char path[SEQ * 8];
    __shared__ int sbest;

    {   // stage ef+eb with all 256 threads
        const float4* sf = (const float4*)(eft + (size_t)b * (SEQ * 8));
        const float4* sb = (const float4*)(ebt + (size_t)b * (SEQ * 8));
        float4* dst = (float4*)ftl;
        #pragma unroll
        for (int i = 0; i < SEQ * 2 / 256; ++i) {
            const int idx = tid + i * 256;
            float4 a = sf[idx];
            const float4 c4 = sb[idx];
            a.x += c4.x; a.y += c4.y; a.z += c4.z; a.w += c4.w;
            dst[idx] = a;
        }
    }
    __syncthreads();

    if (tid < 64) {
        const int lane = tid;
        const int next = lane >> 3;
        const int prev = lane & 7;
        const bool pv = (prev < NTAG);
        const bool nv = (next < NTAG);
        const float trv = (pv && nv) ? (trans[next * NTAG + prev] + b_out[next]) : -3.0e38f;
        float fvp = pv ? ((prev == BOSX) ? 0.0f : NEGC) : -3.0e38f;
        for (int t = 0; t < SEQ; ++t) {
            float mv = fvp + trv;
            int am = prev;
            #pragma unroll
            for (int off = 1; off < 8; off <<= 1) {        // first-max-index semantics
                const float om = __shfl_xor(mv, off);
                const int oa = __shfl_xor(am, off);
                if (om > mv || (om == mv && oa < am)) { mv = om; am = oa; }
            }
            const float fvnew = mv + ftl[t * 8 + next];
            if (prev == 0) bptr_lds[t * 8 + next] = am;
            fvp = __shfl(fvnew, prev << 3);
            if (!pv) fvp = -3.0e38f;
        }
        float term = pv ? (fvp + trans[EOSX * NTAG + prev]) : -3.0e38f;
        int am = prev;
        #pragma unroll
        for (int off = 1; off < 8; off <<= 1) {
            const float om = __shfl_xor(term, off);
            const int oa = __shfl_xor(am, off);
            if (om > term || (om == term && oa < am)) { term = om; am = oa; }
        }
        if (lane == 0) { out[b] = term; sbest = am; }
    }
    __syncthreads();

    if (tid < NTAG) {                                      // 7 concurrent walks, lockstep
        int cur = tid;
        for (int t = SEQ - 1; t >= 0; --t) {
            path[t * 8 + tid] = (unsigned char)cur;
            cur = bptr_lds[t * 8 + cur];
        }
    }
    __syncthreads();
    const int am = sbest;
    for (int t = tid; t < SEQ; t += 256)
        out[BSZ + t * BSZ + b] = (float)path[t * 8 + am];
}

// ======================= launch =======================
extern "C" void kernel_launch(void* const* d_in, const int* in_sizes, int n_in,
                              void* d_out, int out_size, void* d_ws, size_t ws_size,
                              hipStream_t stream)
{
    const int*   sen   = (const int*)d_in[0];
    const float* emb   = (const float*)d_in[1];
    const float* Wih_f = (const float*)d_in[2];
    const float* Whh_f = (const float*)d_in[3];
    const float* b_f   = (const float*)d_in[4];
    const float* Wih_b = (const float*)d_in[5];
    const float* Whh_b = (const float*)d_in[6];
    const float* b_b   = (const float*)d_in[7];
    const float* W_out = (const float*)d_in[8];
    const float* b_out = (const float*)d_in[9];
    const float* trans = (const float*)d_in[10];
    float* out = (float*)d_out;

    char* ws = (char*)d_ws;
    const size_t xw_elems = (size_t)2 * BSZ * SEQ * H4;   // 67,108,864
    const size_t ft_bytes = (size_t)BSZ * SEQ * 8 * 4;    // 2 MB each

    if (ws_size >= xw_elems * 4 + 2 * ft_bytes) {
        float* xw = (float*)ws;
        float* eft = (float*)(ws + xw_elems * 4);
        float* ebt = (float*)(ws + xw_elems * 4 + ft_bytes);
        bilstm_kernel<float><<<dim3(2 * BSZ), dim3(1024), 0, stream>>>(
            sen, emb, Wih_f, b_f, Wih_b, b_b, Whh_f, Whh_b, W_out, xw, eft, ebt);
        vit_kernel<<<dim3(BSZ), dim3(256), 0, stream>>>(eft, ebt, b_out, trans, out);
    } else {
        __hip_bfloat16* xw = (__hip_bfloat16*)ws;
        float* eft = (float*)(ws + xw_elems * 2);
        float* ebt = (float*)(ws + xw_elems * 2 + ft_bytes);
        bilstm_kernel<__hip_bfloat16><<<dim3(2 * BSZ), dim3(1024), 0, stream>>>(
            sen, emb, Wih_f, b_f, Wih_b, b_b, Whh_f, Whh_b, W_out, xw, eft, ebt);
        vit_kernel<<<dim3(BSZ), dim3(256), 0, stream>>>(eft, ebt, b_out, trans, out);
    }
}

// Round 11
// 773.785 us; speedup vs baseline: 1.3075x; 1.1596x over previous
//
#include <hip/hip_runtime.h>
#include <hip/hip_bf16.h>
#include <math.h>
#include <type_traits>

#define SEQ  512
#define BSZ  128
#define EMBD 128
#define H4   512
#define HD   128
#define NTAG 7
#define BOSX 4
#define EOSX 5
#define NEGC (-10000.0f)
#define TILE 16

typedef _Float16 h2 __attribute__((ext_vector_type(2)));

template<typename T> __device__ __forceinline__ void stf(T* p, float v);
template<> __device__ __forceinline__ void stf<float>(float* p, float v) { *p = v; }
template<> __device__ __forceinline__ void stf<__hip_bfloat16>(__hip_bfloat16* p, float v) { *p = __float2bfloat16(v); }

__device__ __forceinline__ float frcp(float x) { return __builtin_amdgcn_rcpf(x); }
__device__ __forceinline__ float bflo(unsigned d) { return __builtin_bit_cast(float, d << 16); }
__device__ __forceinline__ float bfhi(unsigned d) { return __builtin_bit_cast(float, d & 0xFFFF0000u); }

// f16 dot2: 2 MACs/inst, fp32 accumulate (v_dot2_f32_f16)
__device__ __forceinline__ float fdot2(h2 a, h2 b, float c) {
#if __has_builtin(__builtin_amdgcn_fdot2)
    return __builtin_amdgcn_fdot2(a, b, c, false);
#else
    return c + (float)a.x * (float)b.x + (float)a.y * (float)b.y;
#endif
}

template<int C> __device__ __forceinline__ float dppaddf(float x) {
    const int y = __builtin_amdgcn_update_dpp(0, __builtin_bit_cast(int, x), C, 0xF, 0xF, true);
    return x + __builtin_bit_cast(float, y);
}
template<int C> __device__ __forceinline__ float dppmovf(float x) {
    return __builtin_bit_cast(float,
        __builtin_amdgcn_update_dpp(0, __builtin_bit_cast(int, x), C, 0xF, 0xF, true));
}
// k = lane bits {0,1}: full k-reduce = 2 DPP stages
__device__ __forceinline__ float kreduce4(float x) {
    x = dppaddf<0xB1>(x);   // xor bit0
    x = dppaddf<0x4E>(x);   // xor bit1
    return x;
}

// f16 chunk layout: chunk k = 32 f16 = 16 dwords at dword offset 20*k.
// Within one b128 read (sub-offset 4j) the wave's 4 distinct chunk addresses
// hit disjoint bank quads {4j, 4j+20, 4j+8, 4j+28} mod 32 -> conflict-free;
// 16 lanes per address broadcast for free.
#define CH_DW  20
#define ROW_DW 80

// 32-element f16 chunk dot: w[16] half2 x x[16] half2 -> fp32
__device__ __forceinline__ float dot32h(const h2* __restrict__ w, const h2* __restrict__ x) {
    float a = 0.f;
    #pragma unroll
    for (int j = 0; j < 16; ++j) a = fdot2(w[j], x[j], a);
    return a;
}
// load 32 fp32 weights -> 16 half2 (RNE, one-time)
__device__ __forceinline__ void ldwh(h2* w, const float4* wr) {
    #pragma unroll
    for (int j = 0; j < 8; ++j) {
        const float4 f4 = wr[j];
        h2 a; a.x = (_Float16)f4.x; a.y = (_Float16)f4.y;
        h2 b; b.x = (_Float16)f4.z; b.y = (_Float16)f4.w;
        w[2 * j] = a; w[2 * j + 1] = b;
    }
}
__device__ __forceinline__ void unp16(const uint4* p, h2* x) {
    #pragma unroll
    for (int j = 0; j < 4; ++j) {
        x[4 * j]     = __builtin_bit_cast(h2, p[j].x);
        x[4 * j + 1] = __builtin_bit_cast(h2, p[j].y);
        x[4 * j + 2] = __builtin_bit_cast(h2, p[j].z);
        x[4 * j + 3] = __builtin_bit_cast(h2, p[j].w);
    }
}

// =============== K1: fused projection + recurrence + emissions ===============
// grid 2*BSZ (1 block/CU), block 512 = 8 waves: u = wid*16 + (lane>>2),
// k = lane&3 (4-way K-split). R4-R10 held 16 waves / 8-way k constant and the
// ~2950-3800 cyc/step floor never moved across radically different inst mixes
// -> test the untried axis: half the waves per barrier, half the redundant
// issue. Gate ownership q == k: reduce-scatter is 2 DPP stages, xw add and
// proj store are coalesced b32 per lane. Weights f16 in VGPRs (64 regs;
// waves_per_eu(2,2) -> 256-reg budget; R10 proved the attr is honored).
template<typename XWT>
__global__ __launch_bounds__(512) __attribute__((amdgpu_waves_per_eu(2, 2)))
void bilstm_kernel(const int* __restrict__ sen, const float* __restrict__ emb,
                   const float* __restrict__ Wih_f, const float* __restrict__ b_f,
                   const float* __restrict__ Wih_b, const float* __restrict__ b_b,
                   const float* __restrict__ Whh_f, const float* __restrict__ Whh_b,
                   const float* __restrict__ W_out,
                   XWT* __restrict__ xw, float* __restrict__ eft, float* __restrict__ ebt)
{
    const int tid = threadIdx.x;
    const int wid = tid >> 6;
    const int lane = tid & 63;
    const int k = lane & 3;                                // K-chunk / owned gate q
    const int m = lane >> 2;                               // 0..15
    const int u = wid * 16 + m;
    const bool bk0 = (lane & 1) != 0;
    const bool bk1 = (lane & 2) != 0;
    const int chain = blockIdx.x;
    const int dir = chain & 1;
    const int b = chain >> 1;

    __shared__ __align__(16) unsigned smem_u[TILE * H4];   // 32 KB: x-stage (A) / xw tile (B)
    __shared__ __align__(16) unsigned hdb_u[2 * ROW_DW];   // h double-buffer, f16 chunks

    XWT* __restrict__ xw_c = xw + (size_t)chain * (SEQ * H4);
    h2 w2[4][16];                                          // 64 VGPRs of f16 weights

    // ---------------- Phase A: input projection ----------------
    {
        const float* __restrict__ Wih  = dir ? Wih_b : Wih_f;
        const float* __restrict__ bias = dir ? b_b : b_f;
        #pragma unroll
        for (int g = 0; g < 4; ++g)
            ldwh(w2[g], (const float4*)(Wih + (g * HD + u) * EMBD + k * 32));
        const float bj = bias[k * HD + u];                 // my gate's bias

        for (int tt = 0; tt < SEQ; tt += 32) {
            {   // stage 32 embedding rows as f16 chunks: 16 threads/row x 8 floats
                const int srow = tid >> 4;                 // 0..31
                const int p = tid & 15;
                const int tok = sen[(tt + srow) * BSZ + b];
                const float4* er = (const float4*)(emb + (size_t)tok * EMBD + p * 8);
                const float4 v0 = er[0], v1 = er[1];
                uint4 dd;
                h2 t;
                t.x = (_Float16)v0.x; t.y = (_Float16)v0.y; dd.x = __builtin_bit_cast(unsigned, t);
                t.x = (_Float16)v0.z; t.y = (_Float16)v0.w; dd.y = __builtin_bit_cast(unsigned, t);
                t.x = (_Float16)v1.x; t.y = (_Float16)v1.y; dd.z = __builtin_bit_cast(unsigned, t);
                t.x = (_Float16)v1.z; t.y = (_Float16)v1.w; dd.w = __builtin_bit_cast(unsigned, t);
                *(uint4*)&smem_u[srow * ROW_DW + (p >> 2) * CH_DW + (p & 3) * 4] = dd;
            }
            __syncthreads();
            for (int i = 0; i < 32; ++i) {
                const uint4* xr = (const uint4*)(smem_u + i * ROW_DW + k * CH_DW);
                uint4 pk[4];
                #pragma unroll
                for (int j = 0; j < 4; ++j) pk[j] = xr[j];
                h2 hx[16];
                unp16(pk, hx);
                const float pi = dot32h(w2[0], hx);
                const float pf = dot32h(w2[1], hx);
                const float pg = dot32h(w2[2], hx);
                const float po = dot32h(w2[3], hx);
                // reduce-scatter: lane ends owning gate q = k (full sum)
                const float A = (bk0 ? pf : pi) + dppmovf<0xB1>(bk0 ? pi : pf);
                const float B = (bk0 ? po : pg) + dppmovf<0xB1>(bk0 ? pg : po);
                const float z = (bk1 ? B : A) + dppmovf<0x4E>(bk1 ? A : B);
                stf(&xw_c[(tt + i) * H4 + u * 4 + k], z + bj);   // coalesced b32
            }
            __syncthreads();
        }
    }

    // ---------------- Phase B: recurrence + emissions ----------------
    {
        const float* __restrict__ Whh = dir ? Whh_b : Whh_f;
        #pragma unroll
        for (int g = 0; g < 4; ++g)
            ldwh(w2[g], (const float4*)(Whh + (g * HD + u) * HD + k * 32));
        h2 wo[16];                                         // wave-0 emission weights (f16)
        {
            const int mm = (m < NTAG) ? m : 0;
            ldwh(wo, (const float4*)(W_out + mm * 256 + dir * HD + k * 32));
        }
        if (tid < 2 * ROW_DW) hdb_u[tid] = 0u;             // h=0
        float c = 0.0f, v0 = 0.0f, v1 = 0.0f, v2 = 0.0f, v3 = 0.0f;
        float* __restrict__ eX = (dir ? ebt : eft) + (size_t)b * (SEQ * 8);
        float (*xwt)[H4] = (float (*)[H4])smem_u;
        __syncthreads();

        const int t0 = dir ? (SEQ - 1) : 0;
        const int ts = dir ? -1 : 1;
        for (int s = 0; s <= SEQ; ++s) {
            if ((s & (TILE - 1)) == 0) {
                if (s < SEQ) {                             // wave wid stages slots 2wid, 2wid+1
                    #pragma unroll
                    for (int sl = 0; sl < 2; ++sl) {
                        const int slot = wid * 2 + sl;
                        const int tg = t0 + ts * (s + slot);
                        float4* dst = (float4*)xwt[slot];
                        if constexpr (std::is_same_v<XWT, float>) {
                            const float4* src = (const float4*)(xw_c + tg * H4);
                            dst[lane] = src[lane];
                            dst[lane + 64] = src[lane + 64];
                        } else {
                            const uint4 raw = ((const uint4*)(xw_c + tg * H4))[lane];
                            const unsigned rr[4] = {raw.x, raw.y, raw.z, raw.w};
                            float4 lo4, hi4;
                            float* lp = (float*)&lo4; float* hp = (float*)&hi4;
                            #pragma unroll
                            for (int j = 0; j < 2; ++j) {
                                lp[2*j]   = bflo(rr[j]);
                                lp[2*j+1] = bfhi(rr[j]);
                                hp[2*j]   = bflo(rr[j+2]);
                                hp[2*j+1] = bfhi(rr[j+2]);
                            }
                            dst[2 * lane] = lo4;
                            dst[2 * lane + 1] = hi4;
                        }
                    }
                }
                __syncthreads();
            }
            const int cur = s & 1;
            h2 hx[16];                                     // chunk k of h_{t-ts} (f16)
            {
                const uint4* hr = (const uint4*)(hdb_u + cur * ROW_DW + k * CH_DW);
                uint4 pk[4];
                #pragma unroll
                for (int j = 0; j < 4; ++j) pk[j] = hr[j];
                unp16(pk, hx);
            }
            if (s < SEQ) {
                const float xq = xwt[s & (TILE - 1)][u * 4 + k];   // my gate's xw (b32)
                const float pi = dot32h(w2[0], hx);
                const float pf = dot32h(w2[1], hx);
                const float pg = dot32h(w2[2], hx);
                const float po = dot32h(w2[3], hx);
                // reduce-scatter: lane owns gate q = k
                const float A = (bk0 ? pf : pi) + dppmovf<0xB1>(bk0 ? pi : pf);
                const float B = (bk0 ? po : pg) + dppmovf<0xB1>(bk0 ? pg : po);
                float z = (bk1 ? B : A) + dppmovf<0x4E>(bk1 ? A : B);
                z += xq;
                // one activation per lane (gate 2 = tanh via 2*sigma(2z)-1)
                const bool isg = bk1 && !bk0;
                const float x2 = isg ? (z + z) : z;
                float y = frcp(1.0f + __expf(-x2));
                y = isg ? (2.0f * y - 1.0f) : y;
                // all-gather the 4 activated gates
                const float r1 = dppmovf<0xB1>(y);
                const float r2 = dppmovf<0x4E>(y);
                const float r3 = dppmovf<0x4E>(r1);
                const float i0 = bk0 ? r1 : y,  i1 = bk0 ? y : r1;
                const float i2 = bk0 ? r3 : r2, i3 = bk0 ? r2 : r3;
                const float gi = bk1 ? i2 : i0;
                const float gf = bk1 ? i3 : i1;
                const float gg = bk1 ? i0 : i2;
                const float go = bk1 ? i1 : i3;
                c = gf * c + gi * gg;                      // redundant across 4 k-lanes
                const float th = 2.0f * frcp(1.0f + __expf(-2.0f * c)) - 1.0f;
                const float h = go * th;
                if (k == 0) {                              // write h as f16 halfword
                    ((unsigned short*)hdb_u)[((cur ^ 1) * ROW_DW + (u >> 5) * CH_DW) * 2 + (u & 31)]
                        = __builtin_bit_cast(unsigned short, (_Float16)h);
                }
            }
            if (wid == 0 && s >= 1) {                      // emission for time e = s-1
                const float ev = kreduce4(dot32h(wo, hx));
                const int e = s - 1;
                const bool mine = (e & 3) == k;            // e uniform, k lane-varying
                const int j = (e >> 2) & 3;
                v0 = (mine && j == 0) ? ev : v0;
                v1 = (mine && j == 1) ? ev : v1;
                v2 = (mine && j == 2) ? ev : v2;
                v3 = (mine && j == 3) ? ev : v3;
                if ((s & (TILE - 1)) == 0 && m < NTAG) {   // flush e in [s-16, s-1]
                    const int eA = s - TILE + k;
                    eX[(t0 + ts * (eA +  0)) * 8 + m] = v0;
                    eX[(t0 + ts * (eA +  4)) * 8 + m] = v1;
                    eX[(t0 + ts * (eA +  8)) * 8 + m] = v2;
                    eX[(t0 + ts * (eA + 12)) * 8 + m] = v3;
                }
            }
            __syncthreads();
        }
    }
}

// ======================= K2: Viterbi scan + backtrace =======================
// grid BSZ, block 256. Wave 0 runs the scan (lane = next*8+prev); backtrace
// walks all 7 terminal tags concurrently; output writes parallel.
__global__ __launch_bounds__(256, 1)
void vit_kernel(const float* __restrict__ eft, const float* __restrict__ ebt,
                const float* __restrict__ b_out, const float* __restrict__ trans,
                float* __restrict__ out)
{
    const int b = blockIdx.x;
    const int tid = threadIdx.x;
    __shared__ __align__(16) float ftl[SEQ * 8];
    __shared__ int bptr_lds[SEQ * 8];
    __shared__ unsigned char path[SEQ * 8];
    __shared__ int sbest;

    {   // stage ef+eb with all 256 threads
        const float4* sf = (const float4*)(eft + (size_t)b * (SEQ * 8));
        const float4* sb = (const float4*)(ebt + (size_t)b * (SEQ * 8));
        float4* dst = (float4*)ftl;
        #pragma unroll
        for (int i = 0; i < SEQ * 2 / 256; ++i) {
            const int idx = tid + i * 256;
            float4 a = sf[idx];
            const float4 c4 = sb[idx];
            a.x += c4.x; a.y += c4.y; a.z += c4.z; a.w += c4.w;
            dst[idx] = a;
        }
    }
    __syncthreads();

    if (tid < 64) {
        const int lane = tid;
        const int next = lane >> 3;
        const int prev = lane & 7;
        const bool pv = (prev < NTAG);
        const bool nv = (next < NTAG);
        const float trv = (pv && nv) ? (trans[next * NTAG + prev] + b_out[next]) : -3.0e38f;
        float fvp = pv ? ((prev == BOSX) ? 0.0f : NEGC) : -3.0e38f;
        for (int t = 0; t < SEQ; ++t) {
            float mv = fvp + trv;
            int am = prev;
            #pragma unroll
            for (int off = 1; off < 8; off <<= 1) {        // first-max-index semantics
                const float om = __shfl_xor(mv, off);
                const int oa = __shfl_xor(am, off);
                if (om > mv || (om == mv && oa < am)) { mv = om; am = oa; }
            }
            const float fvnew = mv + ftl[t * 8 + next];
            if (prev == 0) bptr_lds[t * 8 + next] = am;
            fvp = __shfl(fvnew, prev << 3);
            if (!pv) fvp = -3.0e38f;
        }
        float term = pv ? (fvp + trans[EOSX * NTAG + prev]) : -3.0e38f;
        int am = prev;
        #pragma unroll
        for (int off = 1; off < 8; off <<= 1) {
            const float om = __shfl_xor(term, off);
            const int oa = __shfl_xor(am, off);
            if (om > term || (om == term && oa < am)) { term = om; am = oa; }
        }
        if (lane == 0) { out[b] = term; sbest = am; }
    }
    __syncthreads();

    if (tid < NTAG) {                                      // 7 concurrent walks, lockstep
        int cur = tid;
        for (int t = SEQ - 1; t >= 0; --t) {
            path[t * 8 + tid] = (unsigned char)cur;
            cur = bptr_lds[t * 8 + cur];
        }
    }
    __syncthreads();
    const int am = sbest;
    for (int t = tid; t < SEQ; t += 256)
        out[BSZ + t * BSZ + b] = (float)path[t * 8 + am];
}

// ======================= launch =======================
extern "C" void kernel_launch(void* const* d_in, const int* in_sizes, int n_in,
                              void* d_out, int out_size, void* d_ws, size_t ws_size,
                              hipStream_t stream)
{
    const int*   sen   = (const int*)d_in[0];
    const float* emb   = (const float*)d_in[1];
    const float* Wih_f = (const float*)d_in[2];
    const float* Whh_f = (const float*)d_in[3];
    const float* b_f   = (const float*)d_in[4];
    const float* Wih_b = (const float*)d_in[5];
    const float* Whh_b = (const float*)d_in[6];
    const float* b_b   = (const float*)d_in[7];
    const float* W_out = (const float*)d_in[8];
    const float* b_out = (const float*)d_in[9];
    const float* trans = (const float*)d_in[10];
    float* out = (float*)d_out;

    char* ws = (char*)d_ws;
    const size_t xw_elems = (size_t)2 * BSZ * SEQ * H4;   // 67,108,864
    const size_t ft_bytes = (size_t)BSZ * SEQ * 8 * 4;    // 2 MB each

    if (ws_size >= xw_elems * 4 + 2 * ft_bytes) {
        float* xw = (float*)ws;
        float* eft = (float*)(ws + xw_elems * 4);
        float* ebt = (float*)(ws + xw_elems * 4 + ft_bytes);
        bilstm_kernel<float><<<dim3(2 * BSZ), dim3(512), 0, stream>>>(
            sen, emb, Wih_f, b_f, Wih_b, b_b, Whh_f, Whh_b, W_out, xw, eft, ebt);
        vit_kernel<<<dim3(BSZ), dim3(256), 0, stream>>>(eft, ebt, b_out, trans, out);
    } else {
        __hip_bfloat16* xw = (__hip_bfloat16*)ws;
        float* eft = (float*)(ws + xw_elems * 2);
        float* ebt = (float*)(ws + xw_elems * 2 + ft_bytes);
        bilstm_kernel<__hip_bfloat16><<<dim3(2 * BSZ), dim3(512), 0, stream>>>(
            sen, emb, Wih_f, b_f, Wih_b, b_b, Whh_f, Whh_b, W_out, xw, eft, ebt);
        vit_kernel<<<dim3(BSZ), dim3(256), 0, stream>>>(eft, ebt, b_out, trans, out);
    }
}